// Round 1
// baseline (1515.757 us; speedup 1.0000x reference)
//
#include <hip/hip_runtime.h>

#define N_NODES 100000
#define N_EDGES 1600000
#define IN_F 128
#define OUT_ALL 64   // HEADS*OUT_F
#define HEADS 4
#define OUT_F 16

// Kernel 1: h = x @ W^T  ([N,128] x [64,128]^T -> [N,64]) plus per-node
// attention dots a_i[N,4], a_j[N,4].
__global__ __launch_bounds__(256) void proj_kernel(
    const float* __restrict__ x, const float* __restrict__ W,
    const float* __restrict__ att_i, const float* __restrict__ att_j,
    float* __restrict__ h, float* __restrict__ ai, float* __restrict__ aj)
{
    __shared__ float Wt[IN_F][OUT_ALL];   // W transposed: Wt[k][o]
    __shared__ float xs[16][132];         // 16 nodes/iter, padded (+4) for banks

    // stage W transposed: consecutive threads -> consecutive o -> conflict-free
    for (int idx = threadIdx.x; idx < IN_F * OUT_ALL; idx += 256) {
        int o = idx & 63, k = idx >> 6;
        Wt[k][o] = W[o * IN_F + k];
    }
    int lsub  = threadIdx.x & 15;   // 16 threads per node
    int og    = lsub * 4;           // this thread's 4 outputs
    int headq = lsub >> 2;          // head of those outputs
    float4 ati = *(const float4*)(att_i + headq * OUT_F + (og & 15));
    float4 atj = *(const float4*)(att_j + headq * OUT_F + (og & 15));
    __syncthreads();

    for (int nodeBase = blockIdx.x * 16; nodeBase < N_NODES;
         nodeBase += gridDim.x * 16) {
        __syncthreads();  // protect xs from previous iteration readers
        // stage 16 x-rows (coalesced float4)
        for (int i = threadIdx.x; i < 16 * 32; i += 256) {
            int n = i >> 5, kq = i & 31;
            int node = nodeBase + n;
            float4 v = (node < N_NODES) ? *(const float4*)(x + node * IN_F + kq * 4)
                                        : float4{0.f, 0.f, 0.f, 0.f};
            *(float4*)(&xs[n][kq * 4]) = v;
        }
        __syncthreads();

        int nloc = threadIdx.x >> 4;
        int node = nodeBase + nloc;
        float4 acc = {0.f, 0.f, 0.f, 0.f};
        for (int k = 0; k < IN_F; ++k) {
            float  xk = xs[nloc][k];
            float4 w4 = *(const float4*)(&Wt[k][og]);
            acc.x += xk * w4.x; acc.y += xk * w4.y;
            acc.z += xk * w4.z; acc.w += xk * w4.w;
        }
        if (node < N_NODES)
            *(float4*)(h + node * OUT_ALL + og) = acc;

        // attention dots, reduce over the 4 threads sharing (node, head)
        float pi = acc.x*ati.x + acc.y*ati.y + acc.z*ati.z + acc.w*ati.w;
        float pj = acc.x*atj.x + acc.y*atj.y + acc.z*atj.z + acc.w*atj.w;
        pi += __shfl_xor(pi, 1, 64); pj += __shfl_xor(pj, 1, 64);
        pi += __shfl_xor(pi, 2, 64); pj += __shfl_xor(pj, 2, 64);
        if (node < N_NODES && (lsub & 3) == 0) {
            ai[node * HEADS + headq] = pi;
            aj[node * HEADS + headq] = pj;
        }
    }
}

// Kernel 2: per edge, 16 lanes/edge. ex = exp(leaky(a_i[dst]+a_j[src]));
// atomically accumulate denom[dst,h] += ex and out[dst,:] += ex*h[src,:].
__global__ __launch_bounds__(256) void edge_kernel(
    const int* __restrict__ ei, const float* __restrict__ h,
    const float* __restrict__ ai, const float* __restrict__ aj,
    float* __restrict__ denom, float* __restrict__ out)
{
    int t    = blockIdx.x * 256 + threadIdx.x;
    int sub  = t & 15;
    int head = sub >> 2;
    int estr = (gridDim.x * 256) >> 4;
    for (int e = t >> 4; e < N_EDGES; e += estr) {
        int src = ei[e];
        int dst = ei[N_EDGES + e];
        float av = ai[dst * HEADS + head] + aj[src * HEADS + head];
        av = av > 0.f ? av : 0.01f * av;
        float ex = __expf(av);
        if ((sub & 3) == 0) atomicAdd(denom + dst * HEADS + head, ex);
        float4 hv = *(const float4*)(h + src * OUT_ALL + sub * 4);
        float* o = out + dst * OUT_ALL + sub * 4;
        atomicAdd(o + 0, ex * hv.x);
        atomicAdd(o + 1, ex * hv.y);
        atomicAdd(o + 2, ex * hv.z);
        atomicAdd(o + 3, ex * hv.w);
    }
}

// Kernel 3: out[n,:] /= (denom[n,h] + 1e-16)
__global__ __launch_bounds__(256) void norm_kernel(
    float* __restrict__ out, const float* __restrict__ denom)
{
    int t = blockIdx.x * 256 + threadIdx.x;   // one float4 per thread
    if (t >= N_NODES * 16) return;
    int node = t >> 4;
    int head = (t & 15) >> 2;
    float inv = 1.0f / (denom[node * HEADS + head] + 1e-16f);
    float4 v = *(float4*)(out + t * 4);
    v.x *= inv; v.y *= inv; v.z *= inv; v.w *= inv;
    *(float4*)(out + t * 4) = v;
}

extern "C" void kernel_launch(void* const* d_in, const int* in_sizes, int n_in,
                              void* d_out, int out_size, void* d_ws, size_t ws_size,
                              hipStream_t stream) {
    const float* x     = (const float*)d_in[0];
    const int*   ei    = (const int*)d_in[1];
    const float* W     = (const float*)d_in[2];
    const float* att_i = (const float*)d_in[3];
    const float* att_j = (const float*)d_in[4];
    float* out = (float*)d_out;

    char* ws = (char*)d_ws;
    float* h     = (float*)(ws);                         // N*64 f32 = 25.6 MB
    float* ai    = (float*)(ws + (size_t)N_NODES * OUT_ALL * 4);          // N*4
    float* aj    = (float*)(ws + (size_t)N_NODES * OUT_ALL * 4 + (size_t)N_NODES * HEADS * 4);
    float* denom = (float*)(ws + (size_t)N_NODES * OUT_ALL * 4 + 2 * (size_t)N_NODES * HEADS * 4);

    hipMemsetAsync(out,   0, (size_t)N_NODES * OUT_ALL * sizeof(float), stream);
    hipMemsetAsync(denom, 0, (size_t)N_NODES * HEADS  * sizeof(float), stream);

    proj_kernel<<<1024, 256, 0, stream>>>(x, W, att_i, att_j, h, ai, aj);
    edge_kernel<<<8192, 256, 0, stream>>>(ei, h, ai, aj, denom, out);
    norm_kernel<<<(N_NODES * 16 + 255) / 256, 256, 0, stream>>>(out, denom);
}

// Round 2
// 340.969 us; speedup vs baseline: 4.4454x; 4.4454x over previous
//
#include <hip/hip_runtime.h>

#define N_NODES 100000
#define N_EDGES 1600000
#define IN_F 128
#define OUT_ALL 64   // HEADS*OUT_F
#define HEADS 4
#define OUT_F 16
#define SCAN_BS 512
#define NSCAN_BLOCKS ((N_NODES + SCAN_BS - 1) / SCAN_BS)   // 196

// ---------------- Kernel 1: projection + per-node attention dots ----------
__global__ __launch_bounds__(256) void proj_kernel(
    const float* __restrict__ x, const float* __restrict__ W,
    const float* __restrict__ att_i, const float* __restrict__ att_j,
    float* __restrict__ h, float* __restrict__ ai, float* __restrict__ aj)
{
    __shared__ float Wt[IN_F][OUT_ALL];   // W transposed: Wt[k][o]
    __shared__ float xs[16][132];         // 16 nodes/iter, padded for banks

    for (int idx = threadIdx.x; idx < IN_F * OUT_ALL; idx += 256) {
        int o = idx & 63, k = idx >> 6;
        Wt[k][o] = W[o * IN_F + k];
    }
    int lsub  = threadIdx.x & 15;   // 16 threads per node
    int og    = lsub * 4;           // this thread's 4 outputs
    int headq = lsub >> 2;
    float4 ati = *(const float4*)(att_i + headq * OUT_F + (og & 15));
    float4 atj = *(const float4*)(att_j + headq * OUT_F + (og & 15));
    __syncthreads();

    for (int nodeBase = blockIdx.x * 16; nodeBase < N_NODES;
         nodeBase += gridDim.x * 16) {
        __syncthreads();
        for (int i = threadIdx.x; i < 16 * 32; i += 256) {
            int n = i >> 5, kq = i & 31;
            int node = nodeBase + n;
            float4 v = (node < N_NODES) ? *(const float4*)(x + node * IN_F + kq * 4)
                                        : float4{0.f, 0.f, 0.f, 0.f};
            *(float4*)(&xs[n][kq * 4]) = v;
        }
        __syncthreads();

        int nloc = threadIdx.x >> 4;
        int node = nodeBase + nloc;
        float4 acc = {0.f, 0.f, 0.f, 0.f};
        for (int k = 0; k < IN_F; ++k) {
            float  xk = xs[nloc][k];
            float4 w4 = *(const float4*)(&Wt[k][og]);
            acc.x += xk * w4.x; acc.y += xk * w4.y;
            acc.z += xk * w4.z; acc.w += xk * w4.w;
        }
        if (node < N_NODES)
            *(float4*)(h + node * OUT_ALL + og) = acc;

        float pi = acc.x*ati.x + acc.y*ati.y + acc.z*ati.z + acc.w*ati.w;
        float pj = acc.x*atj.x + acc.y*atj.y + acc.z*atj.z + acc.w*atj.w;
        pi += __shfl_xor(pi, 1, 64); pj += __shfl_xor(pj, 1, 64);
        pi += __shfl_xor(pi, 2, 64); pj += __shfl_xor(pj, 2, 64);
        if (node < N_NODES && (lsub & 3) == 0) {
            ai[node * HEADS + headq] = pi;
            aj[node * HEADS + headq] = pj;
        }
    }
}

// ---------------- Kernel 2: in-degree histogram --------------------------
__global__ __launch_bounds__(256) void hist_kernel(
    const int* __restrict__ ei, int* __restrict__ counts)
{
    for (int e = blockIdx.x * 256 + threadIdx.x; e < N_EDGES; e += gridDim.x * 256)
        atomicAdd(&counts[ei[N_EDGES + e]], 1);
}

// ---------------- Kernel 3a: block-level exclusive scan -------------------
__global__ __launch_bounds__(SCAN_BS) void scan_block_kernel(
    const int* __restrict__ counts, int* __restrict__ rowptr, int* __restrict__ bsum)
{
    int gid  = blockIdx.x * SCAN_BS + threadIdx.x;
    int v    = (gid < N_NODES) ? counts[gid] : 0;
    int lane = threadIdx.x & 63, wid = threadIdx.x >> 6;
    int incl = v;
    for (int d = 1; d < 64; d <<= 1) {
        int t = __shfl_up(incl, d, 64);
        if (lane >= d) incl += t;
    }
    __shared__ int wsum[SCAN_BS / 64];
    if (lane == 63) wsum[wid] = incl;
    __syncthreads();
    int woff = 0;
    for (int w = 0; w < wid; ++w) woff += wsum[w];
    if (gid < N_NODES) rowptr[gid] = woff + incl - v;
    if (threadIdx.x == SCAN_BS - 1) bsum[blockIdx.x] = woff + incl;
}

// ---------------- Kernel 3b: scan of block sums (1 block) -----------------
__global__ __launch_bounds__(256) void scan_sums_kernel(
    const int* __restrict__ bsum, int* __restrict__ boff)
{
    int v    = (threadIdx.x < NSCAN_BLOCKS) ? bsum[threadIdx.x] : 0;
    int lane = threadIdx.x & 63, wid = threadIdx.x >> 6;
    int incl = v;
    for (int d = 1; d < 64; d <<= 1) {
        int t = __shfl_up(incl, d, 64);
        if (lane >= d) incl += t;
    }
    __shared__ int wsum[4];
    if (lane == 63) wsum[wid] = incl;
    __syncthreads();
    int woff = 0;
    for (int w = 0; w < wid; ++w) woff += wsum[w];
    if (threadIdx.x < NSCAN_BLOCKS) boff[threadIdx.x] = woff + incl - v;
}

// ---------------- Kernel 3c: add block offsets, init cursor ---------------
__global__ __launch_bounds__(256) void addoff_kernel(
    int* __restrict__ rowptr, const int* __restrict__ boff, int* __restrict__ cursor)
{
    int i = blockIdx.x * 256 + threadIdx.x;
    if (i < N_NODES) {
        int r = rowptr[i] + boff[i >> 9];   // SCAN_BS == 512
        rowptr[i] = r;
        cursor[i] = r;
    }
    if (i == 0) rowptr[N_NODES] = N_EDGES;
}

// ---------------- Kernel 4: scatter edges into CSR order ------------------
__global__ __launch_bounds__(256) void scatter_kernel(
    const int* __restrict__ ei, int* __restrict__ cursor, int* __restrict__ srcs)
{
    for (int e = blockIdx.x * 256 + threadIdx.x; e < N_EDGES; e += gridDim.x * 256) {
        int src = ei[e];
        int dst = ei[N_EDGES + e];
        int pos = atomicAdd(&cursor[dst], 1);
        srcs[pos] = src;
    }
}

// ---------------- Kernel 5: per-node gather + online softmax --------------
__global__ __launch_bounds__(256) void gather_kernel(
    const int* __restrict__ rowptr, const int* __restrict__ srcs,
    const float* __restrict__ h, const float* __restrict__ ai,
    const float* __restrict__ aj, float* __restrict__ out)
{
    int node = blockIdx.x * 16 + (threadIdx.x >> 4);
    if (node >= N_NODES) return;
    int sub  = threadIdx.x & 15;
    int head = sub >> 2;
    int beg = rowptr[node], end = rowptr[node + 1];
    float aiv = ai[node * HEADS + head];
    float4 acc = {0.f, 0.f, 0.f, 0.f};
    float  den = 0.f;
    for (int e = beg; e < end; ++e) {
        int src = srcs[e];                       // broadcast across 16 lanes
        float av = aiv + aj[src * HEADS + head];
        av = av > 0.f ? av : 0.01f * av;
        float ex = __expf(av);
        den += ex;
        float4 hv = *(const float4*)(h + src * OUT_ALL + sub * 4);
        acc.x += ex * hv.x; acc.y += ex * hv.y;
        acc.z += ex * hv.z; acc.w += ex * hv.w;
    }
    float inv = 1.0f / (den + 1e-16f);
    acc.x *= inv; acc.y *= inv; acc.z *= inv; acc.w *= inv;
    *(float4*)(out + node * OUT_ALL + sub * 4) = acc;
}

extern "C" void kernel_launch(void* const* d_in, const int* in_sizes, int n_in,
                              void* d_out, int out_size, void* d_ws, size_t ws_size,
                              hipStream_t stream) {
    const float* x     = (const float*)d_in[0];
    const int*   ei    = (const int*)d_in[1];
    const float* W     = (const float*)d_in[2];
    const float* att_i = (const float*)d_in[3];
    const float* att_j = (const float*)d_in[4];
    float* out = (float*)d_out;

    char* ws = (char*)d_ws;
    size_t off = 0;
    auto alloc = [&](size_t bytes) {
        void* p = ws + off;
        off += (bytes + 255) & ~(size_t)255;
        return p;
    };
    float* h      = (float*)alloc((size_t)N_NODES * OUT_ALL * 4);   // 25.6 MB
    float* ai     = (float*)alloc((size_t)N_NODES * HEADS * 4);     // 1.6 MB
    float* aj     = (float*)alloc((size_t)N_NODES * HEADS * 4);     // 1.6 MB
    int*   rowptr = (int*)alloc((size_t)(N_NODES + 1) * 4);
    int*   counts = (int*)alloc((size_t)N_NODES * 4);
    int*   cursor = (int*)alloc((size_t)N_NODES * 4);
    int*   srcs   = (int*)alloc((size_t)N_EDGES * 4);               // 6.4 MB
    int*   bsum   = (int*)alloc(NSCAN_BLOCKS * 4);
    int*   boff   = (int*)alloc(NSCAN_BLOCKS * 4);

    hipMemsetAsync(counts, 0, (size_t)N_NODES * 4, stream);

    proj_kernel<<<1024, 256, 0, stream>>>(x, W, att_i, att_j, h, ai, aj);
    hist_kernel<<<2048, 256, 0, stream>>>(ei, counts);
    scan_block_kernel<<<NSCAN_BLOCKS, SCAN_BS, 0, stream>>>(counts, rowptr, bsum);
    scan_sums_kernel<<<1, 256, 0, stream>>>(bsum, boff);
    addoff_kernel<<<(N_NODES + 255) / 256, 256, 0, stream>>>(rowptr, boff, cursor);
    scatter_kernel<<<2048, 256, 0, stream>>>(ei, cursor, srcs);
    gather_kernel<<<(N_NODES + 15) / 16, 256, 0, stream>>>(rowptr, srcs, h, ai, aj, out);
}

// Round 3
// 286.071 us; speedup vs baseline: 5.2985x; 1.1919x over previous
//
#include <hip/hip_runtime.h>

#define N_NODES 100000
#define N_EDGES 1600000
#define IN_F 128
#define OUT_ALL 64   // HEADS*OUT_F
#define HEADS 4
#define OUT_F 16
#define SCAN_BS 512
#define NSCAN_BLOCKS ((N_NODES + SCAN_BS - 1) / SCAN_BS)   // 196
#define NSLICE 8
#define SLICE_N (N_NODES / NSLICE)    // 12500 exactly

// ---------------- Kernel 1: projection + per-node attention dots ----------
__global__ __launch_bounds__(256) void proj_kernel(
    const float* __restrict__ x, const float* __restrict__ W,
    const float* __restrict__ att_i, const float* __restrict__ att_j,
    float* __restrict__ h, float* __restrict__ ai, float* __restrict__ aj)
{
    __shared__ float Wt[IN_F][OUT_ALL];   // W transposed: Wt[k][o]
    __shared__ float xs[16][132];         // 16 nodes/iter, padded for banks

    for (int idx = threadIdx.x; idx < IN_F * OUT_ALL; idx += 256) {
        int o = idx & 63, k = idx >> 6;
        Wt[k][o] = W[o * IN_F + k];
    }
    int lsub  = threadIdx.x & 15;   // 16 threads per node
    int og    = lsub * 4;           // this thread's 4 outputs
    int headq = lsub >> 2;
    float4 ati = *(const float4*)(att_i + headq * OUT_F + (og & 15));
    float4 atj = *(const float4*)(att_j + headq * OUT_F + (og & 15));
    __syncthreads();

    for (int nodeBase = blockIdx.x * 16; nodeBase < N_NODES;
         nodeBase += gridDim.x * 16) {
        __syncthreads();
        for (int i = threadIdx.x; i < 16 * 32; i += 256) {
            int n = i >> 5, kq = i & 31;
            int node = nodeBase + n;
            float4 v = (node < N_NODES) ? *(const float4*)(x + node * IN_F + kq * 4)
                                        : float4{0.f, 0.f, 0.f, 0.f};
            *(float4*)(&xs[n][kq * 4]) = v;
        }
        __syncthreads();

        int nloc = threadIdx.x >> 4;
        int node = nodeBase + nloc;
        float4 acc = {0.f, 0.f, 0.f, 0.f};
        for (int k = 0; k < IN_F; ++k) {
            float  xk = xs[nloc][k];
            float4 w4 = *(const float4*)(&Wt[k][og]);
            acc.x += xk * w4.x; acc.y += xk * w4.y;
            acc.z += xk * w4.z; acc.w += xk * w4.w;
        }
        if (node < N_NODES)
            *(float4*)(h + node * OUT_ALL + og) = acc;

        float pi = acc.x*ati.x + acc.y*ati.y + acc.z*ati.z + acc.w*ati.w;
        float pj = acc.x*atj.x + acc.y*atj.y + acc.z*atj.z + acc.w*atj.w;
        pi += __shfl_xor(pi, 1, 64); pj += __shfl_xor(pj, 1, 64);
        pi += __shfl_xor(pi, 2, 64); pj += __shfl_xor(pj, 2, 64);
        if (node < N_NODES && (lsub & 3) == 0) {
            ai[node * HEADS + headq] = pi;
            aj[node * HEADS + headq] = pj;
        }
    }
}

// ---------------- Kernel 2: in-degree histogram --------------------------
__global__ __launch_bounds__(256) void hist_kernel(
    const int* __restrict__ ei, int* __restrict__ counts)
{
    for (int e = blockIdx.x * 256 + threadIdx.x; e < N_EDGES; e += gridDim.x * 256)
        atomicAdd(&counts[ei[N_EDGES + e]], 1);
}

// ---------------- Kernel 3a: block-level exclusive scan -------------------
__global__ __launch_bounds__(SCAN_BS) void scan_block_kernel(
    const int* __restrict__ counts, int* __restrict__ rowptr, int* __restrict__ bsum)
{
    int gid  = blockIdx.x * SCAN_BS + threadIdx.x;
    int v    = (gid < N_NODES) ? counts[gid] : 0;
    int lane = threadIdx.x & 63, wid = threadIdx.x >> 6;
    int incl = v;
    for (int d = 1; d < 64; d <<= 1) {
        int t = __shfl_up(incl, d, 64);
        if (lane >= d) incl += t;
    }
    __shared__ int wsum[SCAN_BS / 64];
    if (lane == 63) wsum[wid] = incl;
    __syncthreads();
    int woff = 0;
    for (int w = 0; w < wid; ++w) woff += wsum[w];
    if (gid < N_NODES) rowptr[gid] = woff + incl - v;
    if (threadIdx.x == SCAN_BS - 1) bsum[blockIdx.x] = woff + incl;
}

// ---------------- Kernel 3b: scan of block sums (1 block) -----------------
__global__ __launch_bounds__(256) void scan_sums_kernel(
    const int* __restrict__ bsum, int* __restrict__ boff)
{
    int v    = (threadIdx.x < NSCAN_BLOCKS) ? bsum[threadIdx.x] : 0;
    int lane = threadIdx.x & 63, wid = threadIdx.x >> 6;
    int incl = v;
    for (int d = 1; d < 64; d <<= 1) {
        int t = __shfl_up(incl, d, 64);
        if (lane >= d) incl += t;
    }
    __shared__ int wsum[4];
    if (lane == 63) wsum[wid] = incl;
    __syncthreads();
    int woff = 0;
    for (int w = 0; w < wid; ++w) woff += wsum[w];
    if (threadIdx.x < NSCAN_BLOCKS) boff[threadIdx.x] = woff + incl - v;
}

// ---------------- Kernel 3c: add block offsets, init cursor ---------------
__global__ __launch_bounds__(256) void addoff_kernel(
    int* __restrict__ rowptr, const int* __restrict__ boff, int* __restrict__ cursor)
{
    int i = blockIdx.x * 256 + threadIdx.x;
    if (i < N_NODES) {
        int r = rowptr[i] + boff[i >> 9];   // SCAN_BS == 512
        rowptr[i] = r;
        cursor[i] = r;
    }
    if (i == 0) rowptr[N_NODES] = N_EDGES;
}

// ---------------- Kernel 4: XCD-partitioned scatter into CSR --------------
// blockIdx&7 selects a 12.5K-node dst slice; round-robin block->XCD dispatch
// keeps each srcs/cursor window owned by one XCD's L2 (no cross-XCD line
// ping-pong on the scattered 4B writes).
__global__ __launch_bounds__(256) void scatter_kernel(
    const int* __restrict__ ei, int* __restrict__ cursor, int* __restrict__ srcs)
{
    int grp = blockIdx.x & (NSLICE - 1);
    int lo  = grp * SLICE_N;
    int bio = blockIdx.x >> 3;           // block index within group
    int nb  = gridDim.x >> 3;            // blocks per group
    for (int e = bio * 256 + threadIdx.x; e < N_EDGES; e += nb * 256) {
        int dst = ei[N_EDGES + e];
        if ((unsigned)(dst - lo) < (unsigned)SLICE_N) {
            int pos = atomicAdd(&cursor[dst], 1);
            srcs[pos] = ei[e];
        }
    }
}

// ---------------- Kernel 5: per-node gather + softmax ---------------------
__global__ __launch_bounds__(256) void gather_kernel(
    const int* __restrict__ rowptr, const int* __restrict__ srcs,
    const float* __restrict__ h, const float* __restrict__ ai,
    const float* __restrict__ aj, float* __restrict__ out)
{
    int node = blockIdx.x * 16 + (threadIdx.x >> 4);
    if (node >= N_NODES) return;
    int sub  = threadIdx.x & 15;
    int head = sub >> 2;
    int beg = rowptr[node], end = rowptr[node + 1];
    float aiv = ai[node * HEADS + head];
    float4 acc = {0.f, 0.f, 0.f, 0.f};
    float  den = 0.f;
    for (int e = beg; e < end; ++e) {
        int src = srcs[e];                       // broadcast across 16 lanes
        float av = aiv + aj[src * HEADS + head];
        av = av > 0.f ? av : 0.01f * av;
        float ex = __expf(av);
        den += ex;
        float4 hv = *(const float4*)(h + src * OUT_ALL + sub * 4);
        acc.x += ex * hv.x; acc.y += ex * hv.y;
        acc.z += ex * hv.z; acc.w += ex * hv.w;
    }
    float inv = 1.0f / (den + 1e-16f);
    acc.x *= inv; acc.y *= inv; acc.z *= inv; acc.w *= inv;
    *(float4*)(out + node * OUT_ALL + sub * 4) = acc;
}

extern "C" void kernel_launch(void* const* d_in, const int* in_sizes, int n_in,
                              void* d_out, int out_size, void* d_ws, size_t ws_size,
                              hipStream_t stream) {
    const float* x     = (const float*)d_in[0];
    const int*   ei    = (const int*)d_in[1];
    const float* W     = (const float*)d_in[2];
    const float* att_i = (const float*)d_in[3];
    const float* att_j = (const float*)d_in[4];
    float* out = (float*)d_out;

    char* ws = (char*)d_ws;
    size_t off = 0;
    auto alloc = [&](size_t bytes) {
        void* p = ws + off;
        off += (bytes + 255) & ~(size_t)255;
        return p;
    };
    float* h      = (float*)alloc((size_t)N_NODES * OUT_ALL * 4);   // 25.6 MB
    float* ai     = (float*)alloc((size_t)N_NODES * HEADS * 4);     // 1.6 MB
    float* aj     = (float*)alloc((size_t)N_NODES * HEADS * 4);     // 1.6 MB
    int*   rowptr = (int*)alloc((size_t)(N_NODES + 1) * 4);
    int*   counts = (int*)alloc((size_t)N_NODES * 4);
    int*   cursor = (int*)alloc((size_t)N_NODES * 4);
    int*   srcs   = (int*)alloc((size_t)N_EDGES * 4);               // 6.4 MB
    int*   bsum   = (int*)alloc(NSCAN_BLOCKS * 4);
    int*   boff   = (int*)alloc(NSCAN_BLOCKS * 4);

    hipMemsetAsync(counts, 0, (size_t)N_NODES * 4, stream);

    proj_kernel<<<1024, 256, 0, stream>>>(x, W, att_i, att_j, h, ai, aj);
    hist_kernel<<<2048, 256, 0, stream>>>(ei, counts);
    scan_block_kernel<<<NSCAN_BLOCKS, SCAN_BS, 0, stream>>>(counts, rowptr, bsum);
    scan_sums_kernel<<<1, 256, 0, stream>>>(bsum, boff);
    addoff_kernel<<<(N_NODES + 255) / 256, 256, 0, stream>>>(rowptr, boff, cursor);
    scatter_kernel<<<2048, 256, 0, stream>>>(ei, cursor, srcs);
    gather_kernel<<<(N_NODES + 15) / 16, 256, 0, stream>>>(rowptr, srcs, h, ai, aj, out);
}

// Round 4
// 251.628 us; speedup vs baseline: 6.0238x; 1.1369x over previous
//
#include <hip/hip_runtime.h>

#define N_NODES 100000
#define N_EDGES 1600000
#define IN_F 128
#define OUT_ALL 64   // HEADS*OUT_F
#define HEADS 4
#define OUT_F 16
#define SCAN_BS 512
#define NSCAN_BLOCKS ((N_NODES + SCAN_BS - 1) / SCAN_BS)   // 196
#define NSLICE 8
#define SLICE_N (N_NODES / NSLICE)    // 12500 exactly
#define PROJ_BLOCKS 1024
#define HIST_BLOCKS 1024

static __device__ __forceinline__ ushort f2bf(float f) {
    unsigned u = __float_as_uint(f);
    return (ushort)((u + 0x7FFF + ((u >> 16) & 1)) >> 16);   // RN, no NaN inputs
}
static __device__ __forceinline__ float bf2f(ushort b) {
    return __uint_as_float(((unsigned)b) << 16);
}

// ---- Kernel 1: fused projection (+att dots, bf16 h) and in-degree hist ----
__global__ __launch_bounds__(256) void proj_hist_kernel(
    const float* __restrict__ x, const float* __restrict__ W,
    const float* __restrict__ att_i, const float* __restrict__ att_j,
    const int* __restrict__ ei,
    ushort* __restrict__ hb, float* __restrict__ ai, float* __restrict__ aj,
    int* __restrict__ counts)
{
    if (blockIdx.x >= PROJ_BLOCKS) {           // histogram half of the grid
        int b = blockIdx.x - PROJ_BLOCKS;
        for (int e = b * 256 + threadIdx.x; e < N_EDGES; e += HIST_BLOCKS * 256)
            atomicAdd(&counts[ei[N_EDGES + e]], 1);
        return;
    }

    __shared__ float Wt[IN_F][OUT_ALL];   // W transposed: Wt[k][o]
    __shared__ float xs[16][132];         // 16 nodes/iter, padded for banks

    for (int idx = threadIdx.x; idx < IN_F * OUT_ALL; idx += 256) {
        int o = idx & 63, k = idx >> 6;
        Wt[k][o] = W[o * IN_F + k];
    }
    int lsub  = threadIdx.x & 15;   // 16 threads per node
    int og    = lsub * 4;           // this thread's 4 outputs
    int headq = lsub >> 2;
    float4 ati = *(const float4*)(att_i + headq * OUT_F + (og & 15));
    float4 atj = *(const float4*)(att_j + headq * OUT_F + (og & 15));
    __syncthreads();

    for (int nodeBase = blockIdx.x * 16; nodeBase < N_NODES;
         nodeBase += PROJ_BLOCKS * 16) {
        __syncthreads();
        for (int i = threadIdx.x; i < 16 * 32; i += 256) {
            int n = i >> 5, kq = i & 31;
            int node = nodeBase + n;
            float4 v = (node < N_NODES) ? *(const float4*)(x + node * IN_F + kq * 4)
                                        : float4{0.f, 0.f, 0.f, 0.f};
            *(float4*)(&xs[n][kq * 4]) = v;
        }
        __syncthreads();

        int nloc = threadIdx.x >> 4;
        int node = nodeBase + nloc;
        float4 acc = {0.f, 0.f, 0.f, 0.f};
        for (int k = 0; k < IN_F; ++k) {
            float  xk = xs[nloc][k];
            float4 w4 = *(const float4*)(&Wt[k][og]);
            acc.x += xk * w4.x; acc.y += xk * w4.y;
            acc.z += xk * w4.z; acc.w += xk * w4.w;
        }
        if (node < N_NODES) {
            ushort4 hv;
            hv.x = f2bf(acc.x); hv.y = f2bf(acc.y);
            hv.z = f2bf(acc.z); hv.w = f2bf(acc.w);
            *(ushort4*)(hb + node * OUT_ALL + og) = hv;
        }

        float pi = acc.x*ati.x + acc.y*ati.y + acc.z*ati.z + acc.w*ati.w;
        float pj = acc.x*atj.x + acc.y*atj.y + acc.z*atj.z + acc.w*atj.w;
        pi += __shfl_xor(pi, 1, 64); pj += __shfl_xor(pj, 1, 64);
        pi += __shfl_xor(pi, 2, 64); pj += __shfl_xor(pj, 2, 64);
        if (node < N_NODES && (lsub & 3) == 0) {
            ai[node * HEADS + headq] = pi;
            aj[node * HEADS + headq] = pj;
        }
    }
}

// ---------------- Kernel 2a: block-level exclusive scan -------------------
__global__ __launch_bounds__(SCAN_BS) void scan_block_kernel(
    const int* __restrict__ counts, int* __restrict__ rowptr, int* __restrict__ bsum)
{
    int gid  = blockIdx.x * SCAN_BS + threadIdx.x;
    int v    = (gid < N_NODES) ? counts[gid] : 0;
    int lane = threadIdx.x & 63, wid = threadIdx.x >> 6;
    int incl = v;
    for (int d = 1; d < 64; d <<= 1) {
        int t = __shfl_up(incl, d, 64);
        if (lane >= d) incl += t;
    }
    __shared__ int wsum[SCAN_BS / 64];
    if (lane == 63) wsum[wid] = incl;
    __syncthreads();
    int woff = 0;
    for (int w = 0; w < wid; ++w) woff += wsum[w];
    if (gid < N_NODES) rowptr[gid] = woff + incl - v;
    if (threadIdx.x == SCAN_BS - 1) bsum[blockIdx.x] = woff + incl;
}

// ---------------- Kernel 2b: scan of block sums (1 block) -----------------
__global__ __launch_bounds__(256) void scan_sums_kernel(
    const int* __restrict__ bsum, int* __restrict__ boff)
{
    int v    = (threadIdx.x < NSCAN_BLOCKS) ? bsum[threadIdx.x] : 0;
    int lane = threadIdx.x & 63, wid = threadIdx.x >> 6;
    int incl = v;
    for (int d = 1; d < 64; d <<= 1) {
        int t = __shfl_up(incl, d, 64);
        if (lane >= d) incl += t;
    }
    __shared__ int wsum[4];
    if (lane == 63) wsum[wid] = incl;
    __syncthreads();
    int woff = 0;
    for (int w = 0; w < wid; ++w) woff += wsum[w];
    if (threadIdx.x < NSCAN_BLOCKS) boff[threadIdx.x] = woff + incl - v;
}

// ---------------- Kernel 2c: add block offsets, init cursor ---------------
__global__ __launch_bounds__(256) void addoff_kernel(
    int* __restrict__ rowptr, const int* __restrict__ boff, int* __restrict__ cursor)
{
    int i = blockIdx.x * 256 + threadIdx.x;
    if (i < N_NODES) {
        int r = rowptr[i] + boff[i >> 9];   // SCAN_BS == 512
        rowptr[i] = r;
        cursor[i] = r;
    }
    if (i == 0) rowptr[N_NODES] = N_EDGES;
}

// ---------------- Kernel 3: XCD-partitioned scatter into CSR --------------
__global__ __launch_bounds__(256) void scatter_kernel(
    const int* __restrict__ ei, int* __restrict__ cursor, int* __restrict__ srcs)
{
    int grp = blockIdx.x & (NSLICE - 1);
    int lo  = grp * SLICE_N;
    int bio = blockIdx.x >> 3;           // block index within group
    int nb  = gridDim.x >> 3;            // blocks per group
    for (int e = bio * 256 + threadIdx.x; e < N_EDGES; e += nb * 256) {
        int dst = ei[N_EDGES + e];
        if ((unsigned)(dst - lo) < (unsigned)SLICE_N) {
            int pos = atomicAdd(&cursor[dst], 1);
            srcs[pos] = ei[e];
        }
    }
}

// ---------------- Kernel 4: per-node gather + softmax (bf16 h) ------------
__global__ __launch_bounds__(256) void gather_kernel(
    const int* __restrict__ rowptr, const int* __restrict__ srcs,
    const ushort* __restrict__ hb, const float* __restrict__ ai,
    const float* __restrict__ aj, float* __restrict__ out)
{
    int node = blockIdx.x * 16 + (threadIdx.x >> 4);
    if (node >= N_NODES) return;
    int sub  = threadIdx.x & 15;
    int head = sub >> 2;
    int beg = rowptr[node], end = rowptr[node + 1];
    float aiv = ai[node * HEADS + head];
    float4 acc = {0.f, 0.f, 0.f, 0.f};
    float  den = 0.f;
    for (int e = beg; e < end; ++e) {
        int src = srcs[e];                       // broadcast across 16 lanes
        float av = aiv + aj[src * HEADS + head];
        av = av > 0.f ? av : 0.01f * av;
        float ex = __expf(av);
        den += ex;
        ushort4 hv = *(const ushort4*)(hb + src * OUT_ALL + sub * 4);
        acc.x += ex * bf2f(hv.x); acc.y += ex * bf2f(hv.y);
        acc.z += ex * bf2f(hv.z); acc.w += ex * bf2f(hv.w);
    }
    float inv = 1.0f / (den + 1e-16f);
    acc.x *= inv; acc.y *= inv; acc.z *= inv; acc.w *= inv;
    *(float4*)(out + node * OUT_ALL + sub * 4) = acc;
}

extern "C" void kernel_launch(void* const* d_in, const int* in_sizes, int n_in,
                              void* d_out, int out_size, void* d_ws, size_t ws_size,
                              hipStream_t stream) {
    const float* x     = (const float*)d_in[0];
    const int*   ei    = (const int*)d_in[1];
    const float* W     = (const float*)d_in[2];
    const float* att_i = (const float*)d_in[3];
    const float* att_j = (const float*)d_in[4];
    float* out = (float*)d_out;

    char* ws = (char*)d_ws;
    size_t off = 0;
    auto alloc = [&](size_t bytes) {
        void* p = ws + off;
        off += (bytes + 255) & ~(size_t)255;
        return p;
    };
    ushort* hb     = (ushort*)alloc((size_t)N_NODES * OUT_ALL * 2);  // 12.8 MB
    float*  ai     = (float*)alloc((size_t)N_NODES * HEADS * 4);     // 1.6 MB
    float*  aj     = (float*)alloc((size_t)N_NODES * HEADS * 4);     // 1.6 MB
    int*    rowptr = (int*)alloc((size_t)(N_NODES + 1) * 4);
    int*    counts = (int*)alloc((size_t)N_NODES * 4);
    int*    cursor = (int*)alloc((size_t)N_NODES * 4);
    int*    srcs   = (int*)alloc((size_t)N_EDGES * 4);               // 6.4 MB
    int*    bsum   = (int*)alloc(NSCAN_BLOCKS * 4);
    int*    boff   = (int*)alloc(NSCAN_BLOCKS * 4);

    hipMemsetAsync(counts, 0, (size_t)N_NODES * 4, stream);

    proj_hist_kernel<<<PROJ_BLOCKS + HIST_BLOCKS, 256, 0, stream>>>(
        x, W, att_i, att_j, ei, hb, ai, aj, counts);
    scan_block_kernel<<<NSCAN_BLOCKS, SCAN_BS, 0, stream>>>(counts, rowptr, bsum);
    scan_sums_kernel<<<1, 256, 0, stream>>>(bsum, boff);
    addoff_kernel<<<(N_NODES + 255) / 256, 256, 0, stream>>>(rowptr, boff, cursor);
    scatter_kernel<<<2048, 256, 0, stream>>>(ei, cursor, srcs);
    gather_kernel<<<(N_NODES + 15) / 16, 256, 0, stream>>>(rowptr, srcs, hb, ai, aj, out);
}

// Round 5
// 217.916 us; speedup vs baseline: 6.9557x; 1.1547x over previous
//
#include <hip/hip_runtime.h>

#define N_NODES 100000
#define N_EDGES 1600000
#define IN_F 128
#define OUT_ALL 64   // HEADS*OUT_F
#define HEADS 4
#define OUT_F 16
#define SCAN_BS 512
#define NSCAN_BLOCKS ((N_NODES + SCAN_BS - 1) / SCAN_BS)   // 196
#define NSLICE 8
#define SLICE_N (N_NODES / NSLICE)    // 12500 exactly
#define PROJ_TILES ((N_NODES + 63) / 64)                   // 1563
#define TOTAL_BLOCKS 2084             // 1563 proj (idx&3 != 3) + 521 hist

static __device__ __forceinline__ ushort f2bf(float f) {
    unsigned u = __float_as_uint(f);
    return (ushort)((u + 0x7FFF + ((u >> 16) & 1)) >> 16);   // RN, no NaN inputs
}
static __device__ __forceinline__ float bf2f(ushort b) {
    return __uint_as_float(((unsigned)b) << 16);
}

// ---- Kernel 1: fused projection (register-blocked, bf16 W/h) + histogram ----
// Tile: 64 nodes/block. thread(oq,ng) owns outputs og..og+3 for nodes
// n0..n0+3 -> per k-iter: 1x ushort4 Wt + 4x b32 xs + 16 FMA.
__global__ __launch_bounds__(256) void proj_hist_kernel(
    const float* __restrict__ x, const float* __restrict__ W,
    const float* __restrict__ att_i, const float* __restrict__ att_j,
    const int* __restrict__ ei,
    ushort* __restrict__ hb, float* __restrict__ ai, float* __restrict__ aj,
    int* __restrict__ counts)
{
    if ((blockIdx.x & 3) == 3) {               // histogram quarter of the grid
        int b  = blockIdx.x >> 2;
        int nh = gridDim.x >> 2;               // 521
        for (int e = b * 256 + threadIdx.x; e < N_EDGES; e += nh * 256)
            atomicAdd(&counts[ei[N_EDGES + e]], 1);
        return;
    }
    int tile = blockIdx.x - (blockIdx.x >> 2); // 0..1562

    __shared__ ushort Wt[IN_F][OUT_ALL + 4];   // bf16 W^T, padded  (17 KB)
    __shared__ float  xs[64][132];             // 64 nodes, padded  (33.8 KB)

    for (int idx = threadIdx.x; idx < IN_F * OUT_ALL; idx += 256) {
        int o = idx & 63, k = idx >> 6;
        Wt[k][o] = f2bf(W[o * IN_F + k]);
    }

    int oq   = threadIdx.x & 15;   // output quad 0..15
    int ng   = threadIdx.x >> 4;   // node group 0..15
    int og   = oq * 4;
    int head = oq >> 2;
    int q    = oq & 3;
    float4 ati = *(const float4*)(att_i + head * OUT_F + q * 4);
    float4 atj = *(const float4*)(att_j + head * OUT_F + q * 4);

    int nodeBase = tile * 64;
    // stage 64 x-rows (coalesced float4)
    for (int i = threadIdx.x; i < 64 * 32; i += 256) {
        int n = i >> 5, kq = i & 31;
        int node = nodeBase + n;
        float4 v = (node < N_NODES) ? *(const float4*)(x + node * IN_F + kq * 4)
                                    : float4{0.f, 0.f, 0.f, 0.f};
        *(float4*)(&xs[n][kq * 4]) = v;
    }
    __syncthreads();

    int n0 = ng * 4;
    float4 acc[4] = {{0,0,0,0},{0,0,0,0},{0,0,0,0},{0,0,0,0}};
    #pragma unroll 4
    for (int k = 0; k < IN_F; ++k) {
        ushort4 wv = *(const ushort4*)(&Wt[k][og]);
        float4 w4 = {bf2f(wv.x), bf2f(wv.y), bf2f(wv.z), bf2f(wv.w)};
        float xv[4] = {xs[n0][k], xs[n0+1][k], xs[n0+2][k], xs[n0+3][k]};
        #pragma unroll
        for (int i = 0; i < 4; ++i) {
            acc[i].x += w4.x * xv[i]; acc[i].y += w4.y * xv[i];
            acc[i].z += w4.z * xv[i]; acc[i].w += w4.w * xv[i];
        }
    }

    #pragma unroll
    for (int i = 0; i < 4; ++i) {
        int node = nodeBase + n0 + i;
        if (node < N_NODES) {
            ushort4 hv = {f2bf(acc[i].x), f2bf(acc[i].y),
                          f2bf(acc[i].z), f2bf(acc[i].w)};
            *(ushort4*)(hb + node * OUT_ALL + og) = hv;
        }
        float pi = acc[i].x*ati.x + acc[i].y*ati.y + acc[i].z*ati.z + acc[i].w*ati.w;
        float pj = acc[i].x*atj.x + acc[i].y*atj.y + acc[i].z*atj.z + acc[i].w*atj.w;
        pi += __shfl_xor(pi, 1, 64); pj += __shfl_xor(pj, 1, 64);
        pi += __shfl_xor(pi, 2, 64); pj += __shfl_xor(pj, 2, 64);
        if (node < N_NODES && q == 0) {
            ai[node * HEADS + head] = pi;
            aj[node * HEADS + head] = pj;
        }
    }
}

// ---------------- Kernel 2a: block-level exclusive scan -------------------
__global__ __launch_bounds__(SCAN_BS) void scan_block_kernel(
    const int* __restrict__ counts, int* __restrict__ rowptr, int* __restrict__ bsum)
{
    int gid  = blockIdx.x * SCAN_BS + threadIdx.x;
    int v    = (gid < N_NODES) ? counts[gid] : 0;
    int lane = threadIdx.x & 63, wid = threadIdx.x >> 6;
    int incl = v;
    for (int d = 1; d < 64; d <<= 1) {
        int t = __shfl_up(incl, d, 64);
        if (lane >= d) incl += t;
    }
    __shared__ int wsum[SCAN_BS / 64];
    if (lane == 63) wsum[wid] = incl;
    __syncthreads();
    int woff = 0;
    for (int w = 0; w < wid; ++w) woff += wsum[w];
    if (gid < N_NODES) rowptr[gid] = woff + incl - v;
    if (threadIdx.x == SCAN_BS - 1) bsum[blockIdx.x] = woff + incl;
}

// ---------------- Kernel 2b: scan of block sums (1 block) -----------------
__global__ __launch_bounds__(256) void scan_sums_kernel(
    const int* __restrict__ bsum, int* __restrict__ boff)
{
    int v    = (threadIdx.x < NSCAN_BLOCKS) ? bsum[threadIdx.x] : 0;
    int lane = threadIdx.x & 63, wid = threadIdx.x >> 6;
    int incl = v;
    for (int d = 1; d < 64; d <<= 1) {
        int t = __shfl_up(incl, d, 64);
        if (lane >= d) incl += t;
    }
    __shared__ int wsum[4];
    if (lane == 63) wsum[wid] = incl;
    __syncthreads();
    int woff = 0;
    for (int w = 0; w < wid; ++w) woff += wsum[w];
    if (threadIdx.x < NSCAN_BLOCKS) boff[threadIdx.x] = woff + incl - v;
}

// ---------------- Kernel 2c: add block offsets, init cursor ---------------
__global__ __launch_bounds__(256) void addoff_kernel(
    int* __restrict__ rowptr, const int* __restrict__ boff, int* __restrict__ cursor)
{
    int i = blockIdx.x * 256 + threadIdx.x;
    if (i < N_NODES) {
        int r = rowptr[i] + boff[i >> 9];   // SCAN_BS == 512
        rowptr[i] = r;
        cursor[i] = r;
    }
    if (i == 0) rowptr[N_NODES] = N_EDGES;
}

// ---------------- Kernel 3: XCD-partitioned scatter into CSR --------------
__global__ __launch_bounds__(256) void scatter_kernel(
    const int* __restrict__ ei, int* __restrict__ cursor, int* __restrict__ srcs)
{
    int grp = blockIdx.x & (NSLICE - 1);
    int lo  = grp * SLICE_N;
    int bio = blockIdx.x >> 3;           // block index within group
    int nb  = gridDim.x >> 3;            // blocks per group
    for (int e = bio * 256 + threadIdx.x; e < N_EDGES; e += nb * 256) {
        int dst = ei[N_EDGES + e];
        if ((unsigned)(dst - lo) < (unsigned)SLICE_N) {
            int pos = atomicAdd(&cursor[dst], 1);
            srcs[pos] = ei[e];
        }
    }
}

// ---------------- Kernel 4: per-node gather + softmax (bf16 h) ------------
__global__ __launch_bounds__(256) void gather_kernel(
    const int* __restrict__ rowptr, const int* __restrict__ srcs,
    const ushort* __restrict__ hb, const float* __restrict__ ai,
    const float* __restrict__ aj, float* __restrict__ out)
{
    int node = blockIdx.x * 16 + (threadIdx.x >> 4);
    if (node >= N_NODES) return;
    int sub  = threadIdx.x & 15;
    int head = sub >> 2;
    int beg = rowptr[node], end = rowptr[node + 1];
    float aiv = ai[node * HEADS + head];
    float4 acc = {0.f, 0.f, 0.f, 0.f};
    float  den = 0.f;
    for (int e = beg; e < end; ++e) {
        int src = srcs[e];                       // broadcast across 16 lanes
        float av = aiv + aj[src * HEADS + head];
        av = av > 0.f ? av : 0.01f * av;
        float ex = __expf(av);
        den += ex;
        ushort4 hv = *(const ushort4*)(hb + src * OUT_ALL + sub * 4);
        acc.x += ex * bf2f(hv.x); acc.y += ex * bf2f(hv.y);
        acc.z += ex * bf2f(hv.z); acc.w += ex * bf2f(hv.w);
    }
    float inv = 1.0f / (den + 1e-16f);
    acc.x *= inv; acc.y *= inv; acc.z *= inv; acc.w *= inv;
    *(float4*)(out + node * OUT_ALL + sub * 4) = acc;
}

extern "C" void kernel_launch(void* const* d_in, const int* in_sizes, int n_in,
                              void* d_out, int out_size, void* d_ws, size_t ws_size,
                              hipStream_t stream) {
    const float* x     = (const float*)d_in[0];
    const int*   ei    = (const int*)d_in[1];
    const float* W     = (const float*)d_in[2];
    const float* att_i = (const float*)d_in[3];
    const float* att_j = (const float*)d_in[4];
    float* out = (float*)d_out;

    char* ws = (char*)d_ws;
    size_t off = 0;
    auto alloc = [&](size_t bytes) {
        void* p = ws + off;
        off += (bytes + 255) & ~(size_t)255;
        return p;
    };
    ushort* hb     = (ushort*)alloc((size_t)N_NODES * OUT_ALL * 2);  // 12.8 MB
    float*  ai     = (float*)alloc((size_t)N_NODES * HEADS * 4);     // 1.6 MB
    float*  aj     = (float*)alloc((size_t)N_NODES * HEADS * 4);     // 1.6 MB
    int*    rowptr = (int*)alloc((size_t)(N_NODES + 1) * 4);
    int*    counts = (int*)alloc((size_t)N_NODES * 4);
    int*    cursor = (int*)alloc((size_t)N_NODES * 4);
    int*    srcs   = (int*)alloc((size_t)N_EDGES * 4);               // 6.4 MB
    int*    bsum   = (int*)alloc(NSCAN_BLOCKS * 4);
    int*    boff   = (int*)alloc(NSCAN_BLOCKS * 4);

    hipMemsetAsync(counts, 0, (size_t)N_NODES * 4, stream);

    proj_hist_kernel<<<TOTAL_BLOCKS, 256, 0, stream>>>(
        x, W, att_i, att_j, ei, hb, ai, aj, counts);
    scan_block_kernel<<<NSCAN_BLOCKS, SCAN_BS, 0, stream>>>(counts, rowptr, bsum);
    scan_sums_kernel<<<1, 256, 0, stream>>>(bsum, boff);
    addoff_kernel<<<(N_NODES + 255) / 256, 256, 0, stream>>>(rowptr, boff, cursor);
    scatter_kernel<<<2048, 256, 0, stream>>>(ei, cursor, srcs);
    gather_kernel<<<(N_NODES + 15) / 16, 256, 0, stream>>>(rowptr, srcs, hb, ai, aj, out);
}

// Round 6
// 215.180 us; speedup vs baseline: 7.0441x; 1.0127x over previous
//
#include <hip/hip_runtime.h>

typedef __attribute__((ext_vector_type(8))) short short8;
typedef __attribute__((ext_vector_type(4))) float f32x4;

#define N_NODES 100000
#define N_EDGES 1600000
#define IN_F 128
#define OUT_ALL 64   // HEADS*OUT_F
#define HEADS 4
#define OUT_F 16
#define NTILES (N_NODES / 16)         // 6250 exactly
#define SCAN_BS 512
#define NSCAN_BLOCKS ((N_NODES + SCAN_BS - 1) / SCAN_BS)   // 196
#define NSLICE 8
#define SLICE_N (N_NODES / NSLICE)    // 12500 exactly
#define TOTAL_BLOCKS 2048             // 1536 proj + 512 hist (blockIdx&3==3)

static __device__ __forceinline__ ushort f2bf(float f) {
    unsigned u = __float_as_uint(f);
    return (ushort)((u + 0x7FFF + ((u >> 16) & 1)) >> 16);   // RN, no NaN inputs
}
static __device__ __forceinline__ float bf2f(ushort b) {
    return __uint_as_float(((unsigned)b) << 16);
}
static __device__ __forceinline__ short8 pack_bf16x8(float4 f0, float4 f1) {
    union { unsigned u[4]; short8 s; } r;
    asm("v_cvt_pk_bf16_f32 %0, %1, %2" : "=v"(r.u[0]) : "v"(f0.x), "v"(f0.y));
    asm("v_cvt_pk_bf16_f32 %0, %1, %2" : "=v"(r.u[1]) : "v"(f0.z), "v"(f0.w));
    asm("v_cvt_pk_bf16_f32 %0, %1, %2" : "=v"(r.u[2]) : "v"(f1.x), "v"(f1.y));
    asm("v_cvt_pk_bf16_f32 %0, %1, %2" : "=v"(r.u[3]) : "v"(f1.z), "v"(f1.w));
    return r.s;
}

// ---- Kernel 1: MFMA projection (bf16 in, f32 acc) + fused histogram ------
// Per block: 4 waves = 4 heads. Wave holds W-frags for its 16 output cols
// (all K=128) in regs; grid-strides over 16-node M-tiles.
// Frags (16x16x32 bf16): A[l&15][(l>>4)*8+j], B[k][l&15] (=W-row load),
// D: col=l&15, row=(l>>4)*4+r  (m89-verified layout).
__global__ __launch_bounds__(256) void proj_hist_kernel(
    const float* __restrict__ x, const float* __restrict__ W,
    const float* __restrict__ att_i, const float* __restrict__ att_j,
    const int* __restrict__ ei,
    ushort* __restrict__ hb, float* __restrict__ ai, float* __restrict__ aj,
    int* __restrict__ counts)
{
    if ((blockIdx.x & 3) == 3) {               // histogram quarter of the grid
        int b  = blockIdx.x >> 2;
        int nh = TOTAL_BLOCKS >> 2;            // 512
        for (int e = b * 256 + threadIdx.x; e < N_EDGES; e += nh * 256)
            atomicAdd(&counts[ei[N_EDGES + e]], 1);
        return;
    }
    int bproj = blockIdx.x - (blockIdx.x >> 2);   // 0..1535
    const int nproj = TOTAL_BLOCKS - (TOTAL_BLOCKS >> 2);  // 1536

    int w   = threadIdx.x >> 6;    // wave id == head == 16-col n-tile
    int l   = threadIdx.x & 63;
    int col = l & 15;
    int kg  = l >> 4;              // k-group 0..3 (8 k each)

    // B-frags: rows of W (f32 -> bf16), one per 32-wide K block
    short8 bw[4];
    #pragma unroll
    for (int m = 0; m < 4; ++m) {
        const float* wp = W + (size_t)(w * 16 + col) * IN_F + m * 32 + kg * 8;
        float4 f0 = *(const float4*)wp;
        float4 f1 = *(const float4*)(wp + 4);
        bw[m] = pack_bf16x8(f0, f1);
    }
    float atv_i = att_i[w * OUT_F + col];
    float atv_j = att_j[w * OUT_F + col];

    for (int t = bproj; t < NTILES; t += nproj) {
        int nodeBase = t * 16;
        const float* xp = x + (size_t)(nodeBase + col) * IN_F + kg * 8;
        short8 a[4];
        #pragma unroll
        for (int m = 0; m < 4; ++m) {
            float4 f0 = *(const float4*)(xp + m * 32);
            float4 f1 = *(const float4*)(xp + m * 32 + 4);
            a[m] = pack_bf16x8(f0, f1);
        }
        f32x4 acc = {0.f, 0.f, 0.f, 0.f};
        #pragma unroll
        for (int m = 0; m < 4; ++m)
            acc = __builtin_amdgcn_mfma_f32_16x16x32_bf16(a[m], bw[m], acc, 0, 0, 0);

        // h (bf16) store: lane covers col, rows kg*4+r
        #pragma unroll
        for (int r = 0; r < 4; ++r)
            hb[(size_t)(nodeBase + kg * 4 + r) * OUT_ALL + w * 16 + col] = f2bf(acc[r]);

        // attention dots: reduce acc*att over the 16 cols (lanes of a 16-group)
        float pi0 = acc[0] * atv_i, pi1 = acc[1] * atv_i,
              pi2 = acc[2] * atv_i, pi3 = acc[3] * atv_i;
        float pj0 = acc[0] * atv_j, pj1 = acc[1] * atv_j,
              pj2 = acc[2] * atv_j, pj3 = acc[3] * atv_j;
        #pragma unroll
        for (int d = 1; d < 16; d <<= 1) {
            pi0 += __shfl_xor(pi0, d, 64); pi1 += __shfl_xor(pi1, d, 64);
            pi2 += __shfl_xor(pi2, d, 64); pi3 += __shfl_xor(pi3, d, 64);
            pj0 += __shfl_xor(pj0, d, 64); pj1 += __shfl_xor(pj1, d, 64);
            pj2 += __shfl_xor(pj2, d, 64); pj3 += __shfl_xor(pj3, d, 64);
        }
        if (col == 0) {
            int nb = nodeBase + kg * 4;
            ai[(nb + 0) * HEADS + w] = pi0; aj[(nb + 0) * HEADS + w] = pj0;
            ai[(nb + 1) * HEADS + w] = pi1; aj[(nb + 1) * HEADS + w] = pj1;
            ai[(nb + 2) * HEADS + w] = pi2; aj[(nb + 2) * HEADS + w] = pj2;
            ai[(nb + 3) * HEADS + w] = pi3; aj[(nb + 3) * HEADS + w] = pj3;
        }
    }
}

// ---------------- Kernel 2a: block-level exclusive scan -------------------
__global__ __launch_bounds__(SCAN_BS) void scan_block_kernel(
    const int* __restrict__ counts, int* __restrict__ rowptr, int* __restrict__ bsum)
{
    int gid  = blockIdx.x * SCAN_BS + threadIdx.x;
    int v    = (gid < N_NODES) ? counts[gid] : 0;
    int lane = threadIdx.x & 63, wid = threadIdx.x >> 6;
    int incl = v;
    for (int d = 1; d < 64; d <<= 1) {
        int t = __shfl_up(incl, d, 64);
        if (lane >= d) incl += t;
    }
    __shared__ int wsum[SCAN_BS / 64];
    if (lane == 63) wsum[wid] = incl;
    __syncthreads();
    int woff = 0;
    for (int w = 0; w < wid; ++w) woff += wsum[w];
    if (gid < N_NODES) rowptr[gid] = woff + incl - v;
    if (threadIdx.x == SCAN_BS - 1) bsum[blockIdx.x] = woff + incl;
}

// ---------------- Kernel 2b: scan of block sums (1 block) -----------------
__global__ __launch_bounds__(256) void scan_sums_kernel(
    const int* __restrict__ bsum, int* __restrict__ boff)
{
    int v    = (threadIdx.x < NSCAN_BLOCKS) ? bsum[threadIdx.x] : 0;
    int lane = threadIdx.x & 63, wid = threadIdx.x >> 6;
    int incl = v;
    for (int d = 1; d < 64; d <<= 1) {
        int t = __shfl_up(incl, d, 64);
        if (lane >= d) incl += t;
    }
    __shared__ int wsum[4];
    if (lane == 63) wsum[wid] = incl;
    __syncthreads();
    int woff = 0;
    for (int w = 0; w < wid; ++w) woff += wsum[w];
    if (threadIdx.x < NSCAN_BLOCKS) boff[threadIdx.x] = woff + incl - v;
}

// ---------------- Kernel 2c: add block offsets, init cursor ---------------
__global__ __launch_bounds__(256) void addoff_kernel(
    int* __restrict__ rowptr, const int* __restrict__ boff, int* __restrict__ cursor)
{
    int i = blockIdx.x * 256 + threadIdx.x;
    if (i < N_NODES) {
        int r = rowptr[i] + boff[i >> 9];   // SCAN_BS == 512
        rowptr[i] = r;
        cursor[i] = r;
    }
    if (i == 0) rowptr[N_NODES] = N_EDGES;
}

// ---------------- Kernel 3: XCD-partitioned scatter into CSR --------------
__global__ __launch_bounds__(256) void scatter_kernel(
    const int* __restrict__ ei, int* __restrict__ cursor, int* __restrict__ srcs)
{
    int grp = blockIdx.x & (NSLICE - 1);
    int lo  = grp * SLICE_N;
    int bio = blockIdx.x >> 3;           // block index within group
    int nb  = gridDim.x >> 3;            // blocks per group
    for (int e = bio * 256 + threadIdx.x; e < N_EDGES; e += nb * 256) {
        int dst = ei[N_EDGES + e];
        if ((unsigned)(dst - lo) < (unsigned)SLICE_N) {
            int pos = atomicAdd(&cursor[dst], 1);
            srcs[pos] = ei[e];
        }
    }
}

// ---------------- Kernel 4: per-node gather + softmax (bf16 h) ------------
__global__ __launch_bounds__(256) void gather_kernel(
    const int* __restrict__ rowptr, const int* __restrict__ srcs,
    const ushort* __restrict__ hb, const float* __restrict__ ai,
    const float* __restrict__ aj, float* __restrict__ out)
{
    int node = blockIdx.x * 16 + (threadIdx.x >> 4);
    if (node >= N_NODES) return;
    int sub  = threadIdx.x & 15;
    int head = sub >> 2;
    int beg = rowptr[node], end = rowptr[node + 1];
    float aiv = ai[node * HEADS + head];
    float4 acc = {0.f, 0.f, 0.f, 0.f};
    float  den = 0.f;
    for (int e = beg; e < end; ++e) {
        int src = srcs[e];                       // broadcast across 16 lanes
        float av = aiv + aj[src * HEADS + head];
        av = av > 0.f ? av : 0.01f * av;
        float ex = __expf(av);
        den += ex;
        ushort4 hv = *(const ushort4*)(hb + src * OUT_ALL + sub * 4);
        acc.x += ex * bf2f(hv.x); acc.y += ex * bf2f(hv.y);
        acc.z += ex * bf2f(hv.z); acc.w += ex * bf2f(hv.w);
    }
    float inv = 1.0f / (den + 1e-16f);
    acc.x *= inv; acc.y *= inv; acc.z *= inv; acc.w *= inv;
    *(float4*)(out + node * OUT_ALL + sub * 4) = acc;
}

extern "C" void kernel_launch(void* const* d_in, const int* in_sizes, int n_in,
                              void* d_out, int out_size, void* d_ws, size_t ws_size,
                              hipStream_t stream) {
    const float* x     = (const float*)d_in[0];
    const int*   ei    = (const int*)d_in[1];
    const float* W     = (const float*)d_in[2];
    const float* att_i = (const float*)d_in[3];
    const float* att_j = (const float*)d_in[4];
    float* out = (float*)d_out;

    char* ws = (char*)d_ws;
    size_t off = 0;
    auto alloc = [&](size_t bytes) {
        void* p = ws + off;
        off += (bytes + 255) & ~(size_t)255;
        return p;
    };
    ushort* hb     = (ushort*)alloc((size_t)N_NODES * OUT_ALL * 2);  // 12.8 MB
    float*  ai     = (float*)alloc((size_t)N_NODES * HEADS * 4);     // 1.6 MB
    float*  aj     = (float*)alloc((size_t)N_NODES * HEADS * 4);     // 1.6 MB
    int*    rowptr = (int*)alloc((size_t)(N_NODES + 1) * 4);
    int*    counts = (int*)alloc((size_t)N_NODES * 4);
    int*    cursor = (int*)alloc((size_t)N_NODES * 4);
    int*    srcs   = (int*)alloc((size_t)N_EDGES * 4);               // 6.4 MB
    int*    bsum   = (int*)alloc(NSCAN_BLOCKS * 4);
    int*    boff   = (int*)alloc(NSCAN_BLOCKS * 4);

    hipMemsetAsync(counts, 0, (size_t)N_NODES * 4, stream);

    proj_hist_kernel<<<TOTAL_BLOCKS, 256, 0, stream>>>(
        x, W, att_i, att_j, ei, hb, ai, aj, counts);
    scan_block_kernel<<<NSCAN_BLOCKS, SCAN_BS, 0, stream>>>(counts, rowptr, bsum);
    scan_sums_kernel<<<1, 256, 0, stream>>>(bsum, boff);
    addoff_kernel<<<(N_NODES + 255) / 256, 256, 0, stream>>>(rowptr, boff, cursor);
    scatter_kernel<<<2048, 256, 0, stream>>>(ei, cursor, srcs);
    gather_kernel<<<(N_NODES + 15) / 16, 256, 0, stream>>>(rowptr, srcs, hb, ai, aj, out);
}